// Round 2
// baseline (2675.672 us; speedup 1.0000x reference)
//
#include <hip/hip_runtime.h>
#include <cstdint>
#include <cstddef>

#define B_  64
#define T_  512
#define I_  512
#define H_  1024

typedef float  f32x4  __attribute__((ext_vector_type(4)));
typedef __bf16 bf16x8 __attribute__((ext_vector_type(8)));
typedef unsigned short us4v __attribute__((ext_vector_type(4)));
typedef unsigned int  u32x4 __attribute__((ext_vector_type(4)));
typedef unsigned long long ull;

__device__ __forceinline__ unsigned short f2bf(float f) {
  unsigned int u = __float_as_uint(f);
  u = (u + 0x7fffu + ((u >> 16) & 1u)) >> 16;   // round-to-nearest-even
  return (unsigned short)u;
}

__device__ __forceinline__ float fast_tanh(float x) {
  x = fminf(10.f, fmaxf(-10.f, x));
  float e = __expf(2.f * x);
  return (e - 1.f) * __builtin_amdgcn_rcpf(e + 1.f);
}

// Relaxed agent-scope atomics: coherent at the device coherence point (MALL),
// no cache-maintenance instructions, bypass stale per-XCD L2 caching.
__device__ __forceinline__ void st_ag64(ull* p, ull v) {
  __hip_atomic_store(p, v, __ATOMIC_RELAXED, __HIP_MEMORY_SCOPE_AGENT);
}
__device__ __forceinline__ ull ld_ag64(const ull* p) {
  return __hip_atomic_load(p, __ATOMIC_RELAXED, __HIP_MEMORY_SCOPE_AGENT);
}

// ---------------------------------------------------------------------------
// Transpose fp32 [R][C] -> bf16 [C][R] (K-major layouts for MFMA B-operands)
// ---------------------------------------------------------------------------
__global__ __launch_bounds__(256) void k_transpose_cvt(
    const float* __restrict__ in, unsigned short* __restrict__ out, int R, int C) {
  __shared__ float tile[64][65];
  const int tx = threadIdx.x & 63, ty = threadIdx.x >> 6;
  const int c0 = blockIdx.x * 64, r0 = blockIdx.y * 64;
#pragma unroll
  for (int i = 0; i < 16; i++) {
    int r = i * 4 + ty;
    tile[r][tx] = in[(size_t)(r0 + r) * C + c0 + tx];
  }
  __syncthreads();
#pragma unroll
  for (int i = 0; i < 16; i++) {
    int c = i * 4 + ty;
    out[(size_t)(c0 + c) * R + r0 + tx] = f2bf(tile[tx][c]);
  }
}

// ---------------------------------------------------------------------------
// bias = b_ih + b_hh  (tagged hbuf needs NO init: 0xAA poison is never a tag)
// ---------------------------------------------------------------------------
__global__ __launch_bounds__(256) void k_prep(
    const float* __restrict__ bih, const float* __restrict__ bhh,
    float* __restrict__ bias) {
  int gid = blockIdx.x * 256 + threadIdx.x;
  if (gid < H_) bias[gid] = bih[gid] + bhh[gid];
}

// ---------------------------------------------------------------------------
// Phase 1: xw = x @ w_ih + bias  -> written into d_out's hidden_seq region
// XCD-aware swizzle: bid = 64*ch + 8*n + r -> tileM = 8*ch + r, tileN = n.
// The 8 blocks sharing one x-tile all have bid % 8 == r (same XCD under
// round-robin dispatch) and sit in one 64-bid window (near-concurrent), so
// the 256 KB x-tile is read from HBM once per XCD-L2 instead of 8x.
// ---------------------------------------------------------------------------
__global__ __launch_bounds__(256) void k_gemm_xw(
    const float* __restrict__ x, const unsigned short* __restrict__ wihT,
    const float* __restrict__ bias, float* __restrict__ out) {
  __shared__ __align__(16) unsigned short As[128 * 40];
  __shared__ __align__(16) unsigned short Bs[128 * 40];

  const int tid = threadIdx.x;
  const int bid = blockIdx.x;
  const int tileM = ((bid >> 6) << 3) | (bid & 7);
  const int tileN = (bid >> 3) & 7;
  const int wv = tid >> 6, lane = tid & 63;
  const int row16 = lane & 15, quad = lane >> 4;
  const int m0 = (wv & 1) * 64, n0 = (wv >> 1) * 64;

  f32x4 acc[4][4];
#pragma unroll
  for (int i = 0; i < 4; i++)
#pragma unroll
    for (int j = 0; j < 4; j++) acc[i][j] = (f32x4){0.f, 0.f, 0.f, 0.f};

  const int ar = tid >> 3, ac = (tid & 7) << 2;
  const int br = tid >> 2, bc = (tid & 3) << 3;

#pragma unroll 1
  for (int kt = 0; kt < I_ / 32; kt++) {
    const int k0 = kt * 32;
#pragma unroll
    for (int i = 0; i < 4; i++) {
      int r = ar + i * 32;
      float4 v = *(const float4*)(x + (size_t)(tileM * 128 + r) * I_ + k0 + ac);
      us4v o;
      o.x = f2bf(v.x); o.y = f2bf(v.y); o.z = f2bf(v.z); o.w = f2bf(v.w);
      *(us4v*)(As + r * 40 + ac) = o;
    }
#pragma unroll
    for (int i = 0; i < 2; i++) {
      int r = br + i * 64;
      *(uint4*)(Bs + r * 40 + bc) =
          *(const uint4*)(wihT + (size_t)(tileN * 128 + r) * I_ + k0 + bc);
    }
    __syncthreads();

    bf16x8 af[4], bfr[4];
#pragma unroll
    for (int mt = 0; mt < 4; mt++)
      af[mt] = *(const bf16x8*)(As + (m0 + mt * 16 + row16) * 40 + quad * 8);
#pragma unroll
    for (int nt = 0; nt < 4; nt++)
      bfr[nt] = *(const bf16x8*)(Bs + (n0 + nt * 16 + row16) * 40 + quad * 8);
#pragma unroll
    for (int mt = 0; mt < 4; mt++)
#pragma unroll
      for (int nt = 0; nt < 4; nt++)
        acc[mt][nt] = __builtin_amdgcn_mfma_f32_16x16x32_bf16(
            af[mt], bfr[nt], acc[mt][nt], 0, 0, 0);
    __syncthreads();
  }

#pragma unroll
  for (int mt = 0; mt < 4; mt++)
#pragma unroll
    for (int nt = 0; nt < 4; nt++) {
      int gc = tileN * 128 + n0 + nt * 16 + row16;
      float bv = bias[gc];
#pragma unroll
      for (int r = 0; r < 4; r++) {
        int gr = tileM * 128 + m0 + mt * 16 + quad * 4 + r;
        out[(size_t)gr * H_ + gc] = acc[mt][nt][r] + bv;
      }
    }
}

// ---------------------------------------------------------------------------
// Phase 2: persistent recurrence with DATA-IS-FLAG message passing.
// 64 blocks x 256 threads = 4 groups(16 batches) x 16 column-chunks(64 cols).
// w_hh column fragments stationary in registers (128 VGPRs/lane) -- this
// shape allocated 156 VGPRs in a prior run, i.e. wfrag provably resident
// (the 512-thread variant demoted it: 112 VGPRs, slower).
//
// h exchange: tagged 8B words { hi32 = tag = t+1, lo32 = 2 x bf16 }.
// Single-copy atomicity of the 8B store means tag+payload arrive together:
// NO waitcnt, NO flag array. Consumers poll the data words until all tags
// match. 0xAA ws poison is never a valid tag. Ping-pong parity slots;
// safety: producer can only reach step t+2 (slot reuse) after consuming
// everyone's t+1 data, which implies everyone consumed t's data.
//
// EARLY-ISSUE POLL (new): the 32 tagged loads for step t+1 are issued
// immediately after publishing h_t, BEFORE the epilogue (hidden_seq stores,
// xw prefetch). They fly across the epilogue and the producers' skew; the
// tag check at the top of step t+1 then usually passes on the in-flight
// values, removing store-visibility + poll round-trip latency from the
// serial per-step path. Because the epilogue's HBM ops are issued AFTER the
// poll loads, the compiler's vmcnt wait for the check does not drain them.
// Slot-reuse safety of the early loads: they can only observe poison,
// tag t-1 (stale -> retry), or tag t+1 (valid); the same-parity overwrite
// (tag t+3) requires the producer to first consume OUR h_{t+1}, which we
// haven't published yet.
// ---------------------------------------------------------------------------
__global__ __launch_bounds__(256, 1) void k_scan(
    const unsigned short* __restrict__ whhT,
    unsigned short* __restrict__ hbuf,
    float* __restrict__ out) {
  const int bid = blockIdx.x;
  const int g = bid >> 4, j = bid & 15;
  const int tid = threadIdx.x;
  const int wv = tid >> 6, lane = tid & 63;
  const int row = lane & 15, quad = lane >> 4;
  const int bsl = g * 16;                       // batch slice base
  const int mycol = j * 64 + wv * 16 + row;     // this lane's output column

  // tagged h: [group(4)][parity(2)][8192 words] ull
  ull* hb = (ull*)hbuf;
  ull* gbase = hb + g * 16384;

  // LDS payload broadcast: 2 buffers x 16 rows x 516 u32 (pad 512->516)
  __shared__ __align__(16) unsigned int ldsb[2 * 16 * 516];

  // stationary B-operand: whh[k][mycol], K-major, 32 chunks of K=32
  bf16x8 wfrag[32];
  {
    const unsigned short* wp = whhT + (size_t)mycol * H_ + quad * 8;
#pragma unroll
    for (int kk = 0; kk < 32; kk++)
      wfrag[kk] = *(const bf16x8*)(wp + kk * 32);
  }

  // xw prefetch for t=0
  float xwv[4];
  size_t oi[4];
#pragma unroll
  for (int r = 0; r < 4; r++) {
    int b = bsl + quad * 4 + r;
    oi[r] = ((size_t)b * T_) * H_ + mycol;
    xwv[r] = out[oi[r]];
  }

  ull q[32];   // in-flight tagged words for the NEXT step (early-issued)

  for (int t = 0; t < T_; ++t) {
    f32x4 acc[4];
#pragma unroll
    for (int c = 0; c < 4; c++) acc[c] = (f32x4){0.f, 0.f, 0.f, 0.f};

    if (t > 0) {
      // --- finish early-issued poll: check tags, retry only if stale ---
      const ull* src = gbase + ((t - 1) & 1) * 8192;
      const unsigned int expect = (unsigned int)t;
      for (;;) {
        unsigned int bad = 0u;
#pragma unroll
        for (int i = 0; i < 32; i++)
          bad |= ((unsigned int)(q[i] >> 32)) ^ expect;
        if (__builtin_expect(!bad, 1)) break;
#pragma unroll
        for (int i = 0; i < 32; i++)
          q[i] = ld_ag64(src + i * 256 + tid);
      }

      // --- LDS broadcast: word w=i*256+tid -> lds[(w>>9)*516 + (w&511)] ---
      unsigned int* lw = ldsb + (t & 1) * (16 * 516);
#pragma unroll
      for (int i = 0; i < 32; i++)
        lw[(i >> 1) * 516 + (i & 1) * 256 + tid] = (unsigned int)q[i];
      __syncthreads();

      // --- MFMA from LDS A-fragments ---
      const unsigned int* ap = lw + row * 516 + quad * 4;
#pragma unroll
      for (int kb = 0; kb < 32; kb++) {
        u32x4 w = *(const u32x4*)(ap + kb * 16);     // ds_read_b128
        bf16x8 a = __builtin_bit_cast(bf16x8, w);
        acc[kb & 3] = __builtin_amdgcn_mfma_f32_16x16x32_bf16(
            a, wfrag[kb], acc[kb & 3], 0, 0, 0);
      }
    }
    f32x4 accf = (acc[0] + acc[1]) + (acc[2] + acc[3]);

    // h = tanh(acc + xw); publish tagged bf16 pairs (8B, tag rides along)
    float hv[4];
    ull* dst = gbase + (t & 1) * 8192;
    const ull tagbits = ((ull)(unsigned int)(t + 1)) << 32;
#pragma unroll
    for (int r = 0; r < 4; r++) {
      float h = fast_tanh(accf[r] + xwv[r]);
      hv[r] = h;
      unsigned int myu = (unsigned int)f2bf(h);
      unsigned int pr  = __shfl_xor(myu, 1);
      unsigned int pair = myu | (pr << 16);          // valid on even lanes
      if ((lane & 1) == 0) {
        int b = quad * 4 + r;
        st_ag64(dst + b * 512 + (mycol >> 1), tagbits | (ull)pair);
      }
    }

    // --- EARLY ISSUE: poll loads for next step, before the epilogue ---
    if (t + 1 < T_) {
      const ull* nsrc = gbase + (t & 1) * 8192;
#pragma unroll
      for (int i = 0; i < 32; i++)
        q[i] = ld_ag64(nsrc + i * 256 + tid);
    }
    __builtin_amdgcn_sched_barrier(0);   // publish+poll issue before out[] I/O

    // off-critical-path: hidden_seq stores, h_T tail, next xw prefetch
#pragma unroll
    for (int r = 0; r < 4; r++) {
      out[oi[r]] = hv[r];
      if (t == T_ - 1) {
        int b = bsl + quad * 4 + r;
        out[(size_t)B_ * T_ * H_ + (size_t)b * H_ + mycol] = hv[r];
      }
    }
    if (t + 1 < T_) {
#pragma unroll
      for (int r = 0; r < 4; r++) {
        oi[r] += H_;                 // (b*T + t+1)*H + mycol
        xwv[r] = out[oi[r]];
      }
    }
  }
}

// ---------------------------------------------------------------------------
extern "C" void kernel_launch(void* const* d_in, const int* in_sizes, int n_in,
                              void* d_out, int out_size, void* d_ws, size_t ws_size,
                              hipStream_t stream) {
  const float* x    = (const float*)d_in[0];
  const float* w_ih = (const float*)d_in[1];
  const float* w_hh = (const float*)d_in[2];
  const float* b_ih = (const float*)d_in[3];
  const float* b_hh = (const float*)d_in[4];
  float* out = (float*)d_out;

  char* ws = (char*)d_ws;
  unsigned short* whhT = (unsigned short*)(ws);                       // 2 MB
  unsigned short* wihT = (unsigned short*)(ws + (2u << 20));          // 1 MB
  float*          bias = (float*)(ws + (3u << 20));                   // 4 KB
  unsigned short* hbuf = (unsigned short*)(ws + (3u << 20) + 4096);   // 512 KB tagged

  hipLaunchKernelGGL(k_transpose_cvt, dim3(H_ / 64, H_ / 64), dim3(256), 0, stream,
                     w_hh, whhT, H_, H_);
  hipLaunchKernelGGL(k_transpose_cvt, dim3(H_ / 64, I_ / 64), dim3(256), 0, stream,
                     w_ih, wihT, I_, H_);
  hipLaunchKernelGGL(k_prep, dim3(4), dim3(256), 0, stream, b_ih, b_hh, bias);
  hipLaunchKernelGGL(k_gemm_xw, dim3((B_ * T_ / 128) * (H_ / 128)), dim3(256), 0,
                     stream, x, wihT, bias, out);
  hipLaunchKernelGGL(k_scan, dim3(64), dim3(256), 0, stream, whhT, hbuf, out);
}